// Round 5
// baseline (5792.701 us; speedup 1.0000x reference)
//
#include <hip/hip_runtime.h>
#include <stdint.h>
#include <stddef.h>

typedef __attribute__((ext_vector_type(8))) short short8;
typedef __attribute__((ext_vector_type(4))) float f32x4;

#define MFMA16(A, B, C) __builtin_amdgcn_mfma_f32_16x16x32_bf16((A), (B), (C), 0, 0, 0)

// ---------- workspace layout (bytes) ----------
static const size_t OFF_XB   = 0;                    // x bf16      [64*512, 1024]  67108864
static const size_t OFF_WIH  = 67108864;             // w_ih bf16   [4096, 1024]     8388608
static const size_t OFF_WHH  = 75497472;             // w_hh bf16   [4096, 1024]     8388608
static const size_t OFF_BIAS = 83886080;             // b_ih+b_hh   [4096] f32         16384
static const size_t OFF_H0   = 83902464;             // h buf 0 bf16 [64,1024]        131072
static const size_t OFF_H1   = 84033536;             // h buf 1 bf16                  131072
static const size_t OFF_FLG  = 84164608;             // flags u32[64*8] (32-B stride)
static const size_t OFF_XW   = 84426752;             // xW [512*64, 4096] f32 or bf16
static const size_t XW_F32_BYTES = 536870912;

__device__ __forceinline__ unsigned short f2bf(float f) {
    union { float f; uint32_t u; } v; v.f = f;
    uint32_t u = v.u;
    u += 0x7FFFu + ((u >> 16) & 1u);   // round-to-nearest-even
    return (unsigned short)(u >> 16);
}
__device__ __forceinline__ float bf2f(unsigned short b) {
    union { uint32_t u; float f; } v; v.u = ((uint32_t)b) << 16;
    return v.f;
}

// agent-scope (sc1, L2-bypassing) 16-byte fragment load as 2 x u64 relaxed atomics
__device__ __forceinline__ short8 frag_ld_agent(const unsigned short* p) {
    union { unsigned long long q[2]; short8 s; } u;
    u.q[0] = __hip_atomic_load((const unsigned long long*)p,
                               __ATOMIC_RELAXED, __HIP_MEMORY_SCOPE_AGENT);
    u.q[1] = __hip_atomic_load((const unsigned long long*)(p + 4),
                               __ATOMIC_RELAXED, __HIP_MEMORY_SCOPE_AGENT);
    return u.s;
}

__device__ __forceinline__ float fast_sigmoid(float x) {
    return 1.f / (1.f + __expf(-x));
}
__device__ __forceinline__ float fast_tanh(float x) {
    return 1.f - 2.f / (__expf(2.f * x) + 1.f);
}

// ---------- cast fp32 -> bf16, 4 elems/thread ----------
__global__ __launch_bounds__(256) void cast4_kernel(const float* __restrict__ s,
                                                    unsigned short* __restrict__ d, int n4) {
    int i = blockIdx.x * 256 + threadIdx.x;
    if (i >= n4) return;
    float4 f = ((const float4*)s)[i];
    ushort4 o;
    o.x = f2bf(f.x); o.y = f2bf(f.y); o.z = f2bf(f.z); o.w = f2bf(f.w);
    ((ushort4*)d)[i] = o;
}

// ---------- bias fold + h0 init + flags zero ----------
__global__ __launch_bounds__(256) void init_misc(const float* __restrict__ b_ih,
                                                 const float* __restrict__ b_hh,
                                                 float* __restrict__ bias,
                                                 const float* __restrict__ h0,
                                                 unsigned short* __restrict__ h_ini,
                                                 unsigned int* __restrict__ flags) {
    int i = blockIdx.x * 256 + threadIdx.x;
    if (i < 512) flags[i] = 0u;
    if (i < 4096) bias[i] = b_ih[i] + b_hh[i];
    if (i < 65536) h_ini[i] = f2bf(h0[i]);
}

// ---------- xW GEMM: C[t*64+b][g] = sum_k x[b*512+t][k] * w_ih[g][k] + bias[g] ----------
template <bool XWF32>
__global__ __launch_bounds__(256) void xw_gemm(const unsigned short* __restrict__ xb,
                                               const unsigned short* __restrict__ wb,
                                               const float* __restrict__ bias,
                                               void* __restrict__ xw) {
    __shared__ __align__(16) unsigned short As[128 * 32];
    __shared__ __align__(16) unsigned short Bs[128 * 32];
    const int bm = blockIdx.x, bn = blockIdx.y;
    const int tid = threadIdx.x;
    const int wave = tid >> 6, lane = tid & 63;
    const int wm = (wave >> 1) * 64, wn = (wave & 1) * 64;
    const int lr = lane & 15, lk = (lane >> 4) * 8;

    const int c0 = tid, c1 = tid + 256;
    const int r0 = c0 >> 2, k0c = (c0 & 3) * 8;
    const int r1 = c1 >> 2, k1c = (c1 & 3) * 8;
    const int mA0 = bm * 128 + r0, mA1 = bm * 128 + r1;
    const unsigned short* pa0 = xb + (size_t)(((mA0 & 63) << 9) + (mA0 >> 6)) * 1024 + k0c;
    const unsigned short* pa1 = xb + (size_t)(((mA1 & 63) << 9) + (mA1 >> 6)) * 1024 + k1c;
    const unsigned short* pb0 = wb + (size_t)(bn * 128 + r0) * 1024 + k0c;
    const unsigned short* pb1 = wb + (size_t)(bn * 128 + r1) * 1024 + k1c;
    unsigned short* sa0 = As + r0 * 32 + k0c;
    unsigned short* sa1 = As + r1 * 32 + k1c;
    unsigned short* sb0 = Bs + r0 * 32 + k0c;
    unsigned short* sb1 = Bs + r1 * 32 + k1c;

    f32x4 acc[4][4] = {};

    for (int kk = 0; kk < 32; ++kk) {
        const int ko = kk * 32;
        uint4 av0 = *(const uint4*)(pa0 + ko);
        uint4 av1 = *(const uint4*)(pa1 + ko);
        uint4 bv0 = *(const uint4*)(pb0 + ko);
        uint4 bv1 = *(const uint4*)(pb1 + ko);
        __syncthreads();
        *(uint4*)sa0 = av0;
        *(uint4*)sa1 = av1;
        *(uint4*)sb0 = bv0;
        *(uint4*)sb1 = bv1;
        __syncthreads();
        short8 af[4], bfr[4];
#pragma unroll
        for (int mi = 0; mi < 4; ++mi)
            af[mi] = *(const short8*)(As + (wm + mi * 16 + lr) * 32 + lk);
#pragma unroll
        for (int ni = 0; ni < 4; ++ni)
            bfr[ni] = *(const short8*)(Bs + (wn + ni * 16 + lr) * 32 + lk);
#pragma unroll
        for (int mi = 0; mi < 4; ++mi)
#pragma unroll
            for (int ni = 0; ni < 4; ++ni)
                acc[mi][ni] = MFMA16(af[mi], bfr[ni], acc[mi][ni]);
    }

    const int rbase = (lane >> 4) * 4;
#pragma unroll
    for (int ni = 0; ni < 4; ++ni) {
        const int gc = bn * 128 + wn + ni * 16 + lr;
        const float bv = bias[gc];
#pragma unroll
        for (int mi = 0; mi < 4; ++mi) {
            const int gr = bm * 128 + wm + mi * 16 + rbase;
#pragma unroll
            for (int r = 0; r < 4; ++r) {
                float v = acc[mi][ni][r] + bv;
                if (XWF32) ((float*)xw)[(size_t)(gr + r) * 4096 + gc] = v;
                else ((unsigned short*)xw)[(size_t)(gr + r) * 4096 + gc] = f2bf(v);
            }
        }
    }
}

// ---------- persistent recurrence: 64 blocks x 512 thr, W_hh in REGISTERS ----------
// Block bk owns 64 W rows (4 gates x 16 ch). Waves = K-split-8: wave kq covers
// K in [kq*128, kq*128+128). Per wave: 16 B-frags (4 gate x 4 ksub) = 64 VGPR,
// loaded ONCE via asm volatile global_load_dwordx4 (cannot be rematerialized).
// Per step: 16 A-frags (full 64-batch x K-slice) via sc1 loads, 64 MFMA,
// partials to part[8][64][68] (pad 68: conflict-free stores), 8-way K-reduce,
// gates fp32, h sc1 store -> drain -> flag -> HBM traffic post-flag -> poll -> s_barrier.
template <bool XWF32>
__global__ __launch_bounds__(512, 2) void lstm_persistent(
        unsigned short* hb0, unsigned short* hb1,
        const void* __restrict__ xw,
        const unsigned short* __restrict__ whh,
        const float* __restrict__ fb,
        const float* __restrict__ c0,
        float* __restrict__ out,
        float* __restrict__ hcout,
        unsigned int* flags) {
    __shared__ __align__(16) float part[8 * 64 * 68];   // 139264 B

    const int tid = threadIdx.x;
    const int wave = tid >> 6, lane = tid & 63;
    const int bk = blockIdx.x, ch0 = bk * 16;
    const int kq = wave;                 // K-slice owner
    const int lr = lane & 15, g = lane >> 4;

    // ---- W_hh fragments -> registers, once (volatile: non-rematerializable) ----
    short8 Wf[4][4];   // [gate][ksub]
#pragma unroll
    for (int ni = 0; ni < 4; ++ni)
#pragma unroll
        for (int ks = 0; ks < 4; ++ks) {
            const unsigned short* p = whh + (size_t)(ni * 1024 + ch0 + lr) * 1024
                                          + kq * 128 + ks * 32 + g * 8;
            asm volatile("global_load_dwordx4 %0, %1, off"
                         : "=&v"(Wf[ni][ks]) : "v"(p));
        }
    asm volatile("s_waitcnt vmcnt(0)" ::: "memory");
    __builtin_amdgcn_sched_barrier(0);

    // ---- per-thread epilogue constants: thread owns (batch b, channels ch, ch+1) ----
    const int b  = tid >> 3;
    const int j0 = 2 * (tid & 7);
    const int ch = ch0 + j0;
    const float fb0 = fb[ch], fb1 = fb[ch + 1];
    float c0r = c0[b * 1024 + ch], c1r = c0[b * 1024 + ch + 1];

    // ---- prefetch xW for t=0 ----
    float xwv[4][2];
#pragma unroll
    for (int g4 = 0; g4 < 4; ++g4) {
        if (XWF32) {
            const float2 v = *(const float2*)((const float*)xw + (size_t)b * 4096 + g4 * 1024 + ch);
            xwv[g4][0] = v.x; xwv[g4][1] = v.y;
        } else {
            const uint32_t u = *(const uint32_t*)((const unsigned short*)xw + (size_t)b * 4096 + g4 * 1024 + ch);
            xwv[g4][0] = bf2f((unsigned short)u);
            xwv[g4][1] = bf2f((unsigned short)(u >> 16));
        }
    }

    for (int t = 0; t < 512; ++t) {
        const unsigned short* hp = (t & 1) ? hb1 : hb0;
        unsigned short* hn       = (t & 1) ? hb0 : hb1;

        // ---- A-frags: all 64 batch rows, K-slice kq, via sc1 loads ----
        short8 af[4][4];   // [mi][ksub]
#pragma unroll
        for (int ks = 0; ks < 4; ++ks)
#pragma unroll
            for (int mi = 0; mi < 4; ++mi)
                af[mi][ks] = frag_ld_agent(hp + (size_t)(mi * 16 + lr) * 1024
                                              + kq * 128 + ks * 32 + g * 8);

        // ---- 64 MFMA: acc[mi][ni] over this wave's K-slice ----
        f32x4 acc[4][4] = {};
#pragma unroll
        for (int ks = 0; ks < 4; ++ks)
#pragma unroll
            for (int mi = 0; mi < 4; ++mi)
#pragma unroll
                for (int ni = 0; ni < 4; ++ni)
                    acc[mi][ni] = MFMA16(af[mi][ks], Wf[ni][ks], acc[mi][ni]);

        // ---- partials: part[kq][batch][out] with pad 68 (stores 2-way free) ----
#pragma unroll
        for (int mi = 0; mi < 4; ++mi)
#pragma unroll
            for (int ni = 0; ni < 4; ++ni)
#pragma unroll
                for (int r = 0; r < 4; ++r)
                    part[kq * 4352 + (mi * 16 + g * 4 + r) * 68 + ni * 16 + lr] = acc[mi][ni][r];
        __syncthreads();   // partials visible

        // ---- 8-way K-reduce + gates + state update ----
        float l0[4], l1[4];
#pragma unroll
        for (int g4 = 0; g4 < 4; ++g4) {
            float s0 = xwv[g4][0], s1 = xwv[g4][1];
#pragma unroll
            for (int k8 = 0; k8 < 8; ++k8) {
                const float2 v = *(const float2*)&part[k8 * 4352 + b * 68 + g4 * 16 + j0];
                s0 += v.x; s1 += v.y;
            }
            l0[g4] = s0; l1[g4] = s1;
        }
        const float rg0 = fast_sigmoid(l0[0] - fb0);
        const float fg0 = fast_sigmoid(l0[1] + fb0);
        const float ug0 = fast_tanh(l0[2]);
        const float og0 = fast_sigmoid(l0[3]);
        const float rg1 = fast_sigmoid(l1[0] - fb1);
        const float fg1 = fast_sigmoid(l1[1] + fb1);
        const float ug1 = fast_tanh(l1[2]);
        const float og1 = fast_sigmoid(l1[3]);
        const float of0 = 1.f - fg0, of1 = 1.f - fg1;
        const float gg0 = rg0 * (1.f - of0 * of0) + (1.f - rg0) * (fg0 * fg0);
        const float gg1 = rg1 * (1.f - of1 * of1) + (1.f - rg1) * (fg1 * fg1);
        c0r = gg0 * c0r + (1.f - gg0) * ug0;
        c1r = gg1 * c1r + (1.f - gg1) * ug1;
        const float h0v = og0 * fast_tanh(c0r);
        const float h1v = og1 * fast_tanh(c1r);

        // h (cross-block): one u32 agent-scope store -> straight to L3
        const unsigned hw = ((unsigned)f2bf(h1v) << 16) | (unsigned)f2bf(h0v);
        __hip_atomic_store((unsigned int*)&hn[b * 1024 + ch], hw,
                           __ATOMIC_RELAXED, __HIP_MEMORY_SCOPE_AGENT);

        // ---- drain h store (per-wave vmcnt inside syncthreads), then signal ----
        __syncthreads();
        if (tid == 0)
            __hip_atomic_store(&flags[bk * 8], (unsigned)(t + 1),
                               __ATOMIC_RELAXED, __HIP_MEMORY_SCOPE_AGENT);
        __builtin_amdgcn_sched_barrier(0);   // keep HBM traffic BELOW the flag

        // ---- post-flag: HBM traffic drains in background ----
        *(float2*)&out[((size_t)b * 512 + t) * 1024 + ch] = make_float2(h0v, h1v);
        if (t == 511) {
            *(float2*)&hcout[b * 1024 + ch] = make_float2(h0v, h1v);
            *(float2*)&hcout[65536 + b * 1024 + ch] = make_float2(c0r, c1r);
        }
        {
            const int tp = (t < 511) ? t + 1 : 511;
            const size_t base = ((size_t)tp * 64 + b) * 4096 + ch;
#pragma unroll
            for (int g4 = 0; g4 < 4; ++g4) {
                if (XWF32) {
                    const float2 v = *(const float2*)((const float*)xw + base + g4 * 1024);
                    xwv[g4][0] = v.x; xwv[g4][1] = v.y;
                } else {
                    const uint32_t u = *(const uint32_t*)((const unsigned short*)xw + base + g4 * 1024);
                    xwv[g4][0] = bf2f((unsigned short)u);
                    xwv[g4][1] = bf2f((unsigned short)(u >> 16));
                }
            }
        }

        // ---- wave0 polls all 64 flags (32-B spread); raw s_barrier (no vmcnt drain) ----
        if (wave == 0) {
            const unsigned tgt = (unsigned)(t + 1);
            while (!__all((int)(__hip_atomic_load(&flags[lane * 8], __ATOMIC_RELAXED,
                                                  __HIP_MEMORY_SCOPE_AGENT) >= tgt))) {}
        }
        __builtin_amdgcn_sched_barrier(0);
        __builtin_amdgcn_s_barrier();
    }
}

extern "C" void kernel_launch(void* const* d_in, const int* in_sizes, int n_in,
                              void* d_out, int out_size, void* d_ws, size_t ws_size,
                              hipStream_t stream) {
    const float* x   = (const float*)d_in[0];
    const float* wih = (const float*)d_in[1];
    const float* bih = (const float*)d_in[2];
    const float* whh = (const float*)d_in[3];
    const float* bhh = (const float*)d_in[4];
    const float* fb  = (const float*)d_in[5];
    const float* h0  = (const float*)d_in[6];
    const float* c0  = (const float*)d_in[7];

    char* ws = (char*)d_ws;
    float* out = (float*)d_out;
    float* hc  = out + 33554432;  // h_n, then c_n

    unsigned short* xb   = (unsigned short*)(ws + OFF_XB);
    unsigned short* wihb = (unsigned short*)(ws + OFF_WIH);
    unsigned short* whhb = (unsigned short*)(ws + OFF_WHH);
    float* bias          = (float*)(ws + OFF_BIAS);
    unsigned short* hb0  = (unsigned short*)(ws + OFF_H0);
    unsigned short* hb1  = (unsigned short*)(ws + OFF_H1);
    unsigned int* flags  = (unsigned int*)(ws + OFF_FLG);
    void* xw             = (void*)(ws + OFF_XW);

    const bool f32path = ws_size >= OFF_XW + XW_F32_BYTES;

    cast4_kernel<<<32768, 256, 0, stream>>>(x, xb, 8388608);
    cast4_kernel<<<4096, 256, 0, stream>>>(wih, wihb, 1048576);
    cast4_kernel<<<4096, 256, 0, stream>>>(whh, whhb, 1048576);
    init_misc<<<256, 256, 0, stream>>>(bih, bhh, bias, h0, hb0, flags);

    dim3 g(256, 32);
    if (f32path) xw_gemm<true><<<g, 256, 0, stream>>>(xb, wihb, bias, xw);
    else         xw_gemm<false><<<g, 256, 0, stream>>>(xb, wihb, bias, xw);

    const float* fbp = fb;
    const float* c0p = c0;
    void* xwp = xw;
    const unsigned short* whhp = whhb;
    void* kargs[] = { &hb0, &hb1, &xwp, &whhp, &fbp, &c0p, &out, &hc, &flags };
    if (f32path)
        hipLaunchCooperativeKernel((void*)lstm_persistent<true>, dim3(64), dim3(512),
                                   kargs, 0, stream);
    else
        hipLaunchCooperativeKernel((void*)lstm_persistent<false>, dim3(64), dim3(512),
                                   kargs, 0, stream);
}

// Round 6
// 4328.782 us; speedup vs baseline: 1.3382x; 1.3382x over previous
//
#include <hip/hip_runtime.h>
#include <stdint.h>
#include <stddef.h>

typedef __attribute__((ext_vector_type(8))) short short8;
typedef __attribute__((ext_vector_type(4))) float f32x4;

#define MFMA16(A, B, C) __builtin_amdgcn_mfma_f32_16x16x32_bf16((A), (B), (C), 0, 0, 0)

// ---------- workspace layout (bytes) ----------
static const size_t OFF_XB   = 0;                    // x bf16      [64*512, 1024]  67108864
static const size_t OFF_WIH  = 67108864;             // w_ih bf16   [4096, 1024]     8388608
static const size_t OFF_WHH  = 75497472;             // w_hh bf16   [4096, 1024]     8388608
static const size_t OFF_BIAS = 83886080;             // b_ih+b_hh   [4096] f32         16384
static const size_t OFF_H0   = 83902464;             // h buf 0 bf16 [64,1024]        131072
static const size_t OFF_H1   = 84033536;             // h buf 1 bf16                  131072
static const size_t OFF_FLG  = 84164608;             // flags u32[64*8] (32-B stride)
static const size_t OFF_XW   = 84426752;             // xW [512*64, 4096] f32 or bf16
static const size_t XW_F32_BYTES = 536870912;

__device__ __forceinline__ unsigned short f2bf(float f) {
    union { float f; uint32_t u; } v; v.f = f;
    uint32_t u = v.u;
    u += 0x7FFFu + ((u >> 16) & 1u);   // round-to-nearest-even
    return (unsigned short)(u >> 16);
}
__device__ __forceinline__ float bf2f(unsigned short b) {
    union { uint32_t u; float f; } v; v.u = ((uint32_t)b) << 16;
    return v.f;
}

__device__ __forceinline__ float fast_sigmoid(float x) {
    return 1.f / (1.f + __expf(-x));
}
__device__ __forceinline__ float fast_tanh(float x) {
    return 1.f - 2.f / (__expf(2.f * x) + 1.f);
}

// ---------- cast fp32 -> bf16, 4 elems/thread ----------
__global__ __launch_bounds__(256) void cast4_kernel(const float* __restrict__ s,
                                                    unsigned short* __restrict__ d, int n4) {
    int i = blockIdx.x * 256 + threadIdx.x;
    if (i >= n4) return;
    float4 f = ((const float4*)s)[i];
    ushort4 o;
    o.x = f2bf(f.x); o.y = f2bf(f.y); o.z = f2bf(f.z); o.w = f2bf(f.w);
    ((ushort4*)d)[i] = o;
}

// ---------- bias fold + h0 init + flags zero ----------
__global__ __launch_bounds__(256) void init_misc(const float* __restrict__ b_ih,
                                                 const float* __restrict__ b_hh,
                                                 float* __restrict__ bias,
                                                 const float* __restrict__ h0,
                                                 unsigned short* __restrict__ h_ini,
                                                 unsigned int* __restrict__ flags) {
    int i = blockIdx.x * 256 + threadIdx.x;
    if (i < 512) flags[i] = 0u;
    if (i < 4096) bias[i] = b_ih[i] + b_hh[i];
    if (i < 65536) h_ini[i] = f2bf(h0[i]);
}

// ---------- xW GEMM: C[t*64+b][g] = sum_k x[b*512+t][k] * w_ih[g][k] + bias[g] ----------
template <bool XWF32>
__global__ __launch_bounds__(256) void xw_gemm(const unsigned short* __restrict__ xb,
                                               const unsigned short* __restrict__ wb,
                                               const float* __restrict__ bias,
                                               void* __restrict__ xw) {
    __shared__ __align__(16) unsigned short As[128 * 32];
    __shared__ __align__(16) unsigned short Bs[128 * 32];
    const int bm = blockIdx.x, bn = blockIdx.y;
    const int tid = threadIdx.x;
    const int wave = tid >> 6, lane = tid & 63;
    const int wm = (wave >> 1) * 64, wn = (wave & 1) * 64;
    const int lr = lane & 15, lk = (lane >> 4) * 8;

    const int c0 = tid, c1 = tid + 256;
    const int r0 = c0 >> 2, k0c = (c0 & 3) * 8;
    const int r1 = c1 >> 2, k1c = (c1 & 3) * 8;
    const int mA0 = bm * 128 + r0, mA1 = bm * 128 + r1;
    const unsigned short* pa0 = xb + (size_t)(((mA0 & 63) << 9) + (mA0 >> 6)) * 1024 + k0c;
    const unsigned short* pa1 = xb + (size_t)(((mA1 & 63) << 9) + (mA1 >> 6)) * 1024 + k1c;
    const unsigned short* pb0 = wb + (size_t)(bn * 128 + r0) * 1024 + k0c;
    const unsigned short* pb1 = wb + (size_t)(bn * 128 + r1) * 1024 + k1c;
    unsigned short* sa0 = As + r0 * 32 + k0c;
    unsigned short* sa1 = As + r1 * 32 + k1c;
    unsigned short* sb0 = Bs + r0 * 32 + k0c;
    unsigned short* sb1 = Bs + r1 * 32 + k1c;

    f32x4 acc[4][4] = {};

    for (int kk = 0; kk < 32; ++kk) {
        const int ko = kk * 32;
        uint4 av0 = *(const uint4*)(pa0 + ko);
        uint4 av1 = *(const uint4*)(pa1 + ko);
        uint4 bv0 = *(const uint4*)(pb0 + ko);
        uint4 bv1 = *(const uint4*)(pb1 + ko);
        __syncthreads();
        *(uint4*)sa0 = av0;
        *(uint4*)sa1 = av1;
        *(uint4*)sb0 = bv0;
        *(uint4*)sb1 = bv1;
        __syncthreads();
        short8 af[4], bfr[4];
#pragma unroll
        for (int mi = 0; mi < 4; ++mi)
            af[mi] = *(const short8*)(As + (wm + mi * 16 + lr) * 32 + lk);
#pragma unroll
        for (int ni = 0; ni < 4; ++ni)
            bfr[ni] = *(const short8*)(Bs + (wn + ni * 16 + lr) * 32 + lk);
#pragma unroll
        for (int mi = 0; mi < 4; ++mi)
#pragma unroll
            for (int ni = 0; ni < 4; ++ni)
                acc[mi][ni] = MFMA16(af[mi], bfr[ni], acc[mi][ni]);
    }

    const int rbase = (lane >> 4) * 4;
#pragma unroll
    for (int ni = 0; ni < 4; ++ni) {
        const int gc = bn * 128 + wn + ni * 16 + lr;
        const float bv = bias[gc];
#pragma unroll
        for (int mi = 0; mi < 4; ++mi) {
            const int gr = bm * 128 + wm + mi * 16 + rbase;
#pragma unroll
            for (int r = 0; r < 4; ++r) {
                float v = acc[mi][ni][r] + bv;
                if (XWF32) ((float*)xw)[(size_t)(gr + r) * 4096 + gc] = v;
                else ((unsigned short*)xw)[(size_t)(gr + r) * 4096 + gc] = f2bf(v);
            }
        }
    }
}

// ---------- persistent recurrence: 64 blocks x 512 thr, W_hh in REGISTERS ----------
// Identical to round 5 EXCEPT the h-fragment loads: inline-asm global_load_dwordx4 sc1
// (16 independent loads, ONE vmcnt(0) drain) instead of 32 serialized u64 atomic loads.
template <bool XWF32>
__global__ __launch_bounds__(512, 2) void lstm_persistent(
        unsigned short* hb0, unsigned short* hb1,
        const void* __restrict__ xw,
        const unsigned short* __restrict__ whh,
        const float* __restrict__ fb,
        const float* __restrict__ c0,
        float* __restrict__ out,
        float* __restrict__ hcout,
        unsigned int* flags) {
    __shared__ __align__(16) float part[8 * 64 * 68];   // 139264 B

    const int tid = threadIdx.x;
    const int wave = tid >> 6, lane = tid & 63;
    const int bk = blockIdx.x, ch0 = bk * 16;
    const int kq = wave;                 // K-slice owner
    const int lr = lane & 15, g = lane >> 4;

    // ---- W_hh fragments -> registers, once (volatile: non-rematerializable) ----
    short8 Wf[4][4];   // [gate][ksub]
#pragma unroll
    for (int ni = 0; ni < 4; ++ni)
#pragma unroll
        for (int ks = 0; ks < 4; ++ks) {
            const unsigned short* p = whh + (size_t)(ni * 1024 + ch0 + lr) * 1024
                                          + kq * 128 + ks * 32 + g * 8;
            asm volatile("global_load_dwordx4 %0, %1, off"
                         : "=&v"(Wf[ni][ks]) : "v"(p));
        }
    asm volatile("s_waitcnt vmcnt(0)" ::: "memory");
    __builtin_amdgcn_sched_barrier(0);

    // ---- per-thread epilogue constants: thread owns (batch b, channels ch, ch+1) ----
    const int b  = tid >> 3;
    const int j0 = 2 * (tid & 7);
    const int ch = ch0 + j0;
    const float fb0 = fb[ch], fb1 = fb[ch + 1];
    float c0r = c0[b * 1024 + ch], c1r = c0[b * 1024 + ch + 1];

    // ---- prefetch xW for t=0 ----
    float xwv[4][2];
#pragma unroll
    for (int g4 = 0; g4 < 4; ++g4) {
        if (XWF32) {
            const float2 v = *(const float2*)((const float*)xw + (size_t)b * 4096 + g4 * 1024 + ch);
            xwv[g4][0] = v.x; xwv[g4][1] = v.y;
        } else {
            const uint32_t u = *(const uint32_t*)((const unsigned short*)xw + (size_t)b * 4096 + g4 * 1024 + ch);
            xwv[g4][0] = bf2f((unsigned short)u);
            xwv[g4][1] = bf2f((unsigned short)(u >> 16));
        }
    }

    for (int t = 0; t < 512; ++t) {
        const unsigned short* hp = (t & 1) ? hb1 : hb0;
        unsigned short* hn       = (t & 1) ? hb0 : hb1;

        // ---- A-frags: all 64 batch rows, K-slice kq; 16 PARALLEL sc1 loads ----
        short8 af[4][4];   // [mi][ksub]
        {
            const unsigned short* hbase = hp + (size_t)lr * 1024 + kq * 128 + g * 8;
#pragma unroll
            for (int mi = 0; mi < 4; ++mi) {
                const unsigned short* p = hbase + (size_t)mi * 16 * 1024;
                asm volatile(
                    "global_load_dwordx4 %0, %4, off sc1\n\t"
                    "global_load_dwordx4 %1, %4, off offset:64 sc1\n\t"
                    "global_load_dwordx4 %2, %4, off offset:128 sc1\n\t"
                    "global_load_dwordx4 %3, %4, off offset:192 sc1"
                    : "=&v"(af[mi][0]), "=&v"(af[mi][1]),
                      "=&v"(af[mi][2]), "=&v"(af[mi][3])
                    : "v"(p));
            }
        }
        asm volatile("s_waitcnt vmcnt(0)" ::: "memory");
        __builtin_amdgcn_sched_barrier(0);

        // ---- 64 MFMA: acc[mi][ni] over this wave's K-slice ----
        f32x4 acc[4][4] = {};
#pragma unroll
        for (int ks = 0; ks < 4; ++ks)
#pragma unroll
            for (int mi = 0; mi < 4; ++mi)
#pragma unroll
                for (int ni = 0; ni < 4; ++ni)
                    acc[mi][ni] = MFMA16(af[mi][ks], Wf[ni][ks], acc[mi][ni]);

        // ---- partials: part[kq][batch][out] with pad 68 (stores 2-way free) ----
#pragma unroll
        for (int mi = 0; mi < 4; ++mi)
#pragma unroll
            for (int ni = 0; ni < 4; ++ni)
#pragma unroll
                for (int r = 0; r < 4; ++r)
                    part[kq * 4352 + (mi * 16 + g * 4 + r) * 68 + ni * 16 + lr] = acc[mi][ni][r];
        __syncthreads();   // partials visible

        // ---- 8-way K-reduce + gates + state update ----
        float l0[4], l1[4];
#pragma unroll
        for (int g4 = 0; g4 < 4; ++g4) {
            float s0 = xwv[g4][0], s1 = xwv[g4][1];
#pragma unroll
            for (int k8 = 0; k8 < 8; ++k8) {
                const float2 v = *(const float2*)&part[k8 * 4352 + b * 68 + g4 * 16 + j0];
                s0 += v.x; s1 += v.y;
            }
            l0[g4] = s0; l1[g4] = s1;
        }
        const float rg0 = fast_sigmoid(l0[0] - fb0);
        const float fg0 = fast_sigmoid(l0[1] + fb0);
        const float ug0 = fast_tanh(l0[2]);
        const float og0 = fast_sigmoid(l0[3]);
        const float rg1 = fast_sigmoid(l1[0] - fb1);
        const float fg1 = fast_sigmoid(l1[1] + fb1);
        const float ug1 = fast_tanh(l1[2]);
        const float og1 = fast_sigmoid(l1[3]);
        const float of0 = 1.f - fg0, of1 = 1.f - fg1;
        const float gg0 = rg0 * (1.f - of0 * of0) + (1.f - rg0) * (fg0 * fg0);
        const float gg1 = rg1 * (1.f - of1 * of1) + (1.f - rg1) * (fg1 * fg1);
        c0r = gg0 * c0r + (1.f - gg0) * ug0;
        c1r = gg1 * c1r + (1.f - gg1) * ug1;
        const float h0v = og0 * fast_tanh(c0r);
        const float h1v = og1 * fast_tanh(c1r);

        // h (cross-block): one u32 agent-scope store -> straight to L3
        const unsigned hw = ((unsigned)f2bf(h1v) << 16) | (unsigned)f2bf(h0v);
        __hip_atomic_store((unsigned int*)&hn[b * 1024 + ch], hw,
                           __ATOMIC_RELAXED, __HIP_MEMORY_SCOPE_AGENT);

        // ---- drain h store (per-wave vmcnt inside syncthreads), then signal ----
        __syncthreads();
        if (tid == 0)
            __hip_atomic_store(&flags[bk * 8], (unsigned)(t + 1),
                               __ATOMIC_RELAXED, __HIP_MEMORY_SCOPE_AGENT);
        __builtin_amdgcn_sched_barrier(0);   // keep HBM traffic BELOW the flag

        // ---- post-flag: HBM traffic drains in background ----
        *(float2*)&out[((size_t)b * 512 + t) * 1024 + ch] = make_float2(h0v, h1v);
        if (t == 511) {
            *(float2*)&hcout[b * 1024 + ch] = make_float2(h0v, h1v);
            *(float2*)&hcout[65536 + b * 1024 + ch] = make_float2(c0r, c1r);
        }
        {
            const int tp = (t < 511) ? t + 1 : 511;
            const size_t base = ((size_t)tp * 64 + b) * 4096 + ch;
#pragma unroll
            for (int g4 = 0; g4 < 4; ++g4) {
                if (XWF32) {
                    const float2 v = *(const float2*)((const float*)xw + base + g4 * 1024);
                    xwv[g4][0] = v.x; xwv[g4][1] = v.y;
                } else {
                    const uint32_t u = *(const uint32_t*)((const unsigned short*)xw + base + g4 * 1024);
                    xwv[g4][0] = bf2f((unsigned short)u);
                    xwv[g4][1] = bf2f((unsigned short)(u >> 16));
                }
            }
        }

        // ---- wave0 polls all 64 flags (32-B spread); raw s_barrier (no vmcnt drain) ----
        if (wave == 0) {
            const unsigned tgt = (unsigned)(t + 1);
            while (!__all((int)(__hip_atomic_load(&flags[lane * 8], __ATOMIC_RELAXED,
                                                  __HIP_MEMORY_SCOPE_AGENT) >= tgt))) {}
        }
        __builtin_amdgcn_sched_barrier(0);
        __builtin_amdgcn_s_barrier();
    }
}

extern "C" void kernel_launch(void* const* d_in, const int* in_sizes, int n_in,
                              void* d_out, int out_size, void* d_ws, size_t ws_size,
                              hipStream_t stream) {
    const float* x   = (const float*)d_in[0];
    const float* wih = (const float*)d_in[1];
    const float* bih = (const float*)d_in[2];
    const float* whh = (const float*)d_in[3];
    const float* bhh = (const float*)d_in[4];
    const float* fb  = (const float*)d_in[5];
    const float* h0  = (const float*)d_in[6];
    const float* c0  = (const float*)d_in[7];

    char* ws = (char*)d_ws;
    float* out = (float*)d_out;
    float* hc  = out + 33554432;  // h_n, then c_n

    unsigned short* xb   = (unsigned short*)(ws + OFF_XB);
    unsigned short* wihb = (unsigned short*)(ws + OFF_WIH);
    unsigned short* whhb = (unsigned short*)(ws + OFF_WHH);
    float* bias          = (float*)(ws + OFF_BIAS);
    unsigned short* hb0  = (unsigned short*)(ws + OFF_H0);
    unsigned short* hb1  = (unsigned short*)(ws + OFF_H1);
    unsigned int* flags  = (unsigned int*)(ws + OFF_FLG);
    void* xw             = (void*)(ws + OFF_XW);

    const bool f32path = ws_size >= OFF_XW + XW_F32_BYTES;

    cast4_kernel<<<32768, 256, 0, stream>>>(x, xb, 8388608);
    cast4_kernel<<<4096, 256, 0, stream>>>(wih, wihb, 1048576);
    cast4_kernel<<<4096, 256, 0, stream>>>(whh, whhb, 1048576);
    init_misc<<<256, 256, 0, stream>>>(bih, bhh, bias, h0, hb0, flags);

    dim3 g(256, 32);
    if (f32path) xw_gemm<true><<<g, 256, 0, stream>>>(xb, wihb, bias, xw);
    else         xw_gemm<false><<<g, 256, 0, stream>>>(xb, wihb, bias, xw);

    const float* fbp = fb;
    const float* c0p = c0;
    void* xwp = xw;
    const unsigned short* whhp = whhb;
    void* kargs[] = { &hb0, &hb1, &xwp, &whhp, &fbp, &c0p, &out, &hc, &flags };
    if (f32path)
        hipLaunchCooperativeKernel((void*)lstm_persistent<true>, dim3(64), dim3(512),
                                   kargs, 0, stream);
    else
        hipLaunchCooperativeKernel((void*)lstm_persistent<false>, dim3(64), dim3(512),
                                   kargs, 0, stream);
}